// Round 13
// baseline (16.681 us; speedup 1.0000x reference)
//
#include <hip/hip_runtime.h>
#include <float.h>

#define INPUT_DIM 2304
#define SUB_DIM 64
#define ATOMS 512
#define NUM_EXPERTS 256
#define TOPK 4

// offset = 1/sqrt(2304) = 1/48 exactly
#define OFFSET (1.0f / 48.0f)
#define MAGIC 0x9E3779B9u

typedef unsigned long long u64;

// ---- payload-in-flag: single 8B relaxed agent atomics (sc1, L3 coherence point) ----
__device__ __forceinline__ u64 pair_ld(const u64* p) {
    return __hip_atomic_load(p, __ATOMIC_RELAXED, __HIP_MEMORY_SCOPE_AGENT);
}
__device__ __forceinline__ void pair_st(u64* p, u64 v) {
    __hip_atomic_store(p, v, __ATOMIC_RELAXED, __HIP_MEMORY_SCOPE_AGENT);
}
__device__ __forceinline__ u64 pack(float f) {
    return ((u64)__float_as_uint(f) << 32) | (u64)MAGIC;
}
__device__ __forceinline__ bool pvalid(u64 v) { return (unsigned)v == MAGIC; }
__device__ __forceinline__ float payload(u64 v) { return __uint_as_float((unsigned)(v >> 32)); }
__device__ __forceinline__ float dot4(float4 a, float4 b) {
    return a.x * b.x + a.y * b.y + a.z * b.z + a.w * b.w;
}

// ws layout (u64 units):
//   pc[256 readers][256 rows]                  @ 0        (512 KB)
//   ps[16 copies][256 rows][4 wave-partials]   @ 65536    (128 KB)
//   pd[36 readers][4 experts][16 six.][64]     @ 81920    (1.13 MB)
// MAGIC protocol; every slot has exactly ONE consumer which resets it to 0.
// Poison 0xAA.. != MAGIC -> first call works; resets keep replays honest.
//
// Roles (grid = 256 blocks exactly, 1 block/CU):
//   all blocks    : P1 code row b, P2 local top-4, P3 sub row b (sync-free publish)
//   b in [44,108) : P4 expert sixteenth (e=(b-44)>>4, q=(b-44)&15, 32 atoms)
//   b in [8,44)   : P5 recon (64 output dims each)
//   others        : retire after P3

__global__ void __launch_bounds__(256, 1) moe_fused(
    const float* __restrict__ x,
    const float* __restrict__ enc_top,
    const float* __restrict__ W_down,
    const float* __restrict__ enc_w,
    float* __restrict__ out,
    float* __restrict__ ws_f)
{
    u64* pc = (u64*)ws_f;           // [256][256]
    u64* ps = pc + 256 * 256;       // [16][256][4]
    u64* pd = ps + 16 * 256 * 4;    // [36][4][16][64]

    __shared__ float s_red[256];
    __shared__ float s_sub[SUB_DIM];
    __shared__ float s_ec[32];                // per-sixteenth atoms
    __shared__ float s_decp[16][SUB_DIM];     // decode partials / recon reduce buffer
    __shared__ float s_dec[SUB_DIM];
    __shared__ int   s_idx[TOPK];
    __shared__ float s_val[TOPK];

    const int b    = blockIdx.x;    // 0..255
    const int t    = threadIdx.x;   // 0..255
    const int lane = t & 63;
    const int wave = t >> 6;
    const float4* x4 = (const float4*)x;

    // ================= P1: code row b (256-thread dot, <=3 indep loads) =================
    {
        const float4* row4 = (const float4*)(enc_top + (size_t)b * INPUT_DIM);
        float acc = dot4(row4[t], x4[t]) + dot4(row4[t + 256], x4[t + 256]);
        if (t < 64) acc += dot4(row4[t + 512], x4[t + 512]);
        #pragma unroll
        for (int o = 32; o > 0; o >>= 1) acc += __shfl_down(acc, o);
        if (lane == 0) s_red[wave] = acc;
        __syncthreads();
        // every thread folds the 4 wave partials itself (no broadcast round trip)
        float c = (s_red[0] + s_red[1]) + (s_red[2] + s_red[3]);
        c = (c >= OFFSET) ? c : 0.0f;
        pair_st(&pc[(size_t)t * 256 + b], pack(c));   // one 8B store per thread -> reader t
    }

    // ================= P2: wave0 polls 256 codes, local top-4 =================
    if (wave == 0) {
        u64 v0, v1, v2, v3;
        for (;;) {
            v0 = pair_ld(&pc[(size_t)b * 256 + lane]);
            v1 = pair_ld(&pc[(size_t)b * 256 + lane + 64]);
            v2 = pair_ld(&pc[(size_t)b * 256 + lane + 128]);
            v3 = pair_ld(&pc[(size_t)b * 256 + lane + 192]);
            if (__all(pvalid(v0) && pvalid(v1) && pvalid(v2) && pvalid(v3))) break;
        }
        float v[4] = { payload(v0), payload(v1), payload(v2), payload(v3) };
        int   id[4] = { lane, lane + 64, lane + 128, lane + 192 };
        for (int k = 0; k < TOPK; ++k) {
            float bv = v[0]; int bi = id[0];
            #pragma unroll
            for (int i = 1; i < 4; ++i)
                if (v[i] > bv || (v[i] == bv && id[i] < bi)) { bv = v[i]; bi = id[i]; }
            #pragma unroll
            for (int o = 32; o > 0; o >>= 1) {
                float ov = __shfl_down(bv, o);
                int   oi = __shfl_down(bi, o);
                if (ov > bv || (ov == bv && oi < bi)) { bv = ov; bi = oi; }
            }
            bv = __shfl(bv, 0);
            bi = __shfl(bi, 0);
            if (lane == 0) { s_idx[k] = bi; s_val[k] = bv; }
            #pragma unroll
            for (int i = 0; i < 4; ++i)
                if (id[i] == bi) v[i] = -FLT_MAX;
        }
        // reset consumed pairs (off critical path)
        pair_st(&pc[(size_t)b * 256 + lane], 0ull);
        pair_st(&pc[(size_t)b * 256 + lane + 64], 0ull);
        pair_st(&pc[(size_t)b * 256 + lane + 128], 0ull);
        pair_st(&pc[(size_t)b * 256 + lane + 192], 0ull);
    }
    __syncthreads();

    // ===== P4 prefetch issue (expert blocks 44..107), fire-and-forget before P3 =====
    const float* Wq = nullptr;
    float pf = 0.0f;
    if (b >= 44 && b < 108) {
        const int eb = b - 44;
        const int e  = eb >> 4, q = eb & 15;
        Wq = enc_w + ((size_t)s_idx[e] * ATOMS + (size_t)q * 32) * SUB_DIM;
        // touch one float4 per 64B line: 128 lines; threads 128..255 duplicate (harmless)
        float4 w = ((const float4*)Wq)[(size_t)(t & 127) * 4];
        pf = w.x + w.w;
    }

    // ================= P3: sub row b — sync-free butterfly + per-wave partial publish ====
    {
        const int E = s_idx[b >> 6];
        const float4* row4 = (const float4*)(W_down + ((size_t)E * SUB_DIM + (b & 63)) * INPUT_DIM);
        float acc = dot4(row4[t], x4[t]) + dot4(row4[t + 256], x4[t + 256]);
        if (t < 64) acc += dot4(row4[t + 512], x4[t + 512]);
        #pragma unroll
        for (int o = 32; o > 0; o >>= 1) acc += __shfl_xor(acc, o);   // all lanes hold wave partial
        if (lane < 16)
            pair_st(&ps[((size_t)lane * 256 + b) * 4 + wave], pack(acc));  // 16 copies x 4 partials
    }

    if (b < 8 || b >= 108) return;    // plain producers retire

    // ================= P4: expert encode+decode, 16 sixteenth-blocks per expert ==========
    if (b >= 44) {
        const int eb = b - 44;
        const int e  = eb >> 4, q = eb & 15;
        if (wave == 0) {
            const size_t sbase = ((size_t)q * 256 + e * SUB_DIM + lane) * 4;
            u64 w0, w1, w2, w3;
            for (;;) {
                w0 = pair_ld(&ps[sbase]);
                w1 = pair_ld(&ps[sbase + 1]);
                w2 = pair_ld(&ps[sbase + 2]);
                w3 = pair_ld(&ps[sbase + 3]);
                if (__all(pvalid(w0) && pvalid(w1) && pvalid(w2) && pvalid(w3))) break;
            }
            s_sub[lane] = (payload(w0) + payload(w1)) + (payload(w2) + payload(w3));
            pair_st(&ps[sbase], 0ull);
            pair_st(&ps[sbase + 1], 0ull);
            pair_st(&ps[sbase + 2], 0ull);
            pair_st(&ps[sbase + 3], 0ull);
        }
        asm volatile("" :: "v"(pf));   // keep prefetch alive
        // encode: wave0-local (s_sub written & read by wave 0 -> lgkmcnt ordering, no barrier)
        if (t < 32) {
            const float4* row4 = (const float4*)(Wq + (size_t)t * SUB_DIM);
            float acc = 0.0f;
            #pragma unroll
            for (int i = 0; i < SUB_DIM / 4; ++i) {
                float4 w = row4[i];
                acc += w.x * s_sub[4*i] + w.y * s_sub[4*i+1] + w.z * s_sub[4*i+2] + w.w * s_sub[4*i+3];
            }
            s_ec[t] = (acc >= OFFSET) ? acc : 0.01f * acc;   // leaky slope .01
        }
        __syncthreads();
        // decode partial over 32 atoms: thread (ch=t>>4, sg=t&15) -> 2 atoms x 4 s-cols
        {
            const int sg = t & 15, ch = t >> 4;
            float4 a4 = make_float4(0.f, 0.f, 0.f, 0.f);
            #pragma unroll
            for (int aa = ch * 2; aa < ch * 2 + 2; ++aa) {
                float4 w = *(const float4*)(Wq + (size_t)aa * SUB_DIM + sg * 4);
                float  ec = s_ec[aa];
                a4.x += w.x * ec; a4.y += w.y * ec; a4.z += w.z * ec; a4.w += w.w * ec;
            }
            *(float4*)&s_decp[ch][sg * 4] = a4;
        }
        __syncthreads();
        if (t < SUB_DIM) {
            float d = 0.0f;
            #pragma unroll
            for (int c = 0; c < 16; ++c) d += s_decp[c][t];
            s_dec[t] = d;
        }
        __syncthreads();
        // fan-out sixteenth-partial dec to 36 readers
        {
            const u64 pv = pack(s_dec[lane]);
            #pragma unroll
            for (int i = 0; i < 9; ++i) {
                const int r = wave + 4 * i;   // 0..35
                pair_st(&pd[(((size_t)r * TOPK + e) * 16 + q) * 64 + lane], pv);
            }
        }
        return;
    }

    // ================= P5: recon (blocks 8..43); W preloaded during P4 window =================
    {
        const int rb = b - 8;                  // 0..35
        const int d  = rb * 64 + lane;
        const int E  = s_idx[wave];            // one expert per wave
        float wr[SUB_DIM];
        const float* Wb = W_down + (size_t)E * SUB_DIM * INPUT_DIM + d;
        #pragma unroll
        for (int s = 0; s < SUB_DIM; ++s) wr[s] = Wb[(size_t)s * INPUT_DIM];
        const float et = s_val[wave] * enc_top[(size_t)E * INPUT_DIM + d];
        // poll the 16 sixteenth-dec partials for this wave's expert
        const size_t base = ((size_t)rb * TOPK + wave) * 16 * 64 + lane;
        u64 v[16];
        for (;;) {
            bool ok = true;
            #pragma unroll
            for (int i = 0; i < 16; ++i) v[i] = pair_ld(&pd[base + (size_t)i * 64]);
            #pragma unroll
            for (int i = 0; i < 16; ++i) ok = ok && pvalid(v[i]);
            if (__all(ok)) break;
        }
        float dv = 0.0f;
        {
            float p0 = 0.f, p1 = 0.f, p2 = 0.f, p3 = 0.f;
            #pragma unroll
            for (int i = 0; i < 16; i += 4) {
                p0 += payload(v[i]);
                p1 += payload(v[i + 1]);
                p2 += payload(v[i + 2]);
                p3 += payload(v[i + 3]);
            }
            dv = (p0 + p1) + (p2 + p3);
        }
        #pragma unroll
        for (int i = 0; i < 16; ++i) pair_st(&pd[base + (size_t)i * 64], 0ull);
        // split-accumulator shfl dot (depth ~16 instead of 64)
        float a0 = 0.f, a1 = 0.f, a2 = 0.f, a3 = 0.f;
        #pragma unroll
        for (int s = 0; s < SUB_DIM; s += 4) {
            a0 += wr[s]     * __shfl(dv, s);
            a1 += wr[s + 1] * __shfl(dv, s + 1);
            a2 += wr[s + 2] * __shfl(dv, s + 2);
            a3 += wr[s + 3] * __shfl(dv, s + 3);
        }
        // cross-wave reduce in s_decp (no P3 LDS use anymore -> no extra barrier needed)
        float* red = (float*)s_decp;
        red[t] = et + ((a0 + a1) + (a2 + a3));
        __syncthreads();
        if (t < 64)
            out[rb * 64 + t] = red[t] + red[t + 64] + red[t + 128] + red[t + 192];
    }
}

extern "C" void kernel_launch(void* const* d_in, const int* in_sizes, int n_in,
                              void* d_out, int out_size, void* d_ws, size_t ws_size,
                              hipStream_t stream) {
    const float* x       = (const float*)d_in[0];
    const float* enc_top = (const float*)d_in[1];
    const float* W_down  = (const float*)d_in[2];
    const float* enc_w   = (const float*)d_in[3];
    float* out = (float*)d_out;
    float* ws  = (float*)d_ws;

    moe_fused<<<dim3(256), dim3(256), 0, stream>>>(x, enc_top, W_down, enc_w, out, ws);
}

// Round 14
// 15.973 us; speedup vs baseline: 1.0443x; 1.0443x over previous
//
#include <hip/hip_runtime.h>
#include <float.h>

#define INPUT_DIM 2304
#define SUB_DIM 64
#define ATOMS 512
#define NUM_EXPERTS 256
#define TOPK 4

// offset = 1/sqrt(2304) = 1/48 exactly
#define OFFSET (1.0f / 48.0f)
#define MAGIC 0x9E3779B9u

typedef unsigned long long u64;

// ---- payload-in-flag: single 8B relaxed agent atomics (sc1, L3 coherence point) ----
__device__ __forceinline__ u64 pair_ld(const u64* p) {
    return __hip_atomic_load(p, __ATOMIC_RELAXED, __HIP_MEMORY_SCOPE_AGENT);
}
__device__ __forceinline__ void pair_st(u64* p, u64 v) {
    __hip_atomic_store(p, v, __ATOMIC_RELAXED, __HIP_MEMORY_SCOPE_AGENT);
}
__device__ __forceinline__ u64 pack(float f) {
    return ((u64)__float_as_uint(f) << 32) | (u64)MAGIC;
}
__device__ __forceinline__ bool pvalid(u64 v) { return (unsigned)v == MAGIC; }
__device__ __forceinline__ float payload(u64 v) { return __uint_as_float((unsigned)(v >> 32)); }
__device__ __forceinline__ float dot4(float4 a, float4 b) {
    return a.x * b.x + a.y * b.y + a.z * b.z + a.w * b.w;
}

// ws layout (u64 units):
//   pc[256 readers][256 rows]                @ 0       (512 KB)
//   ps[8 eighth-copies][256 rows]            @ 65536   (16 KB)
//   pd[36 readers][4 experts][8 eighths][64] @ 67584   (576 KB)
// MAGIC protocol; every slot has exactly ONE consumer which resets it to 0.
// Poison 0xAA.. != MAGIC -> first call works; resets keep replays honest.
//
// Roles (grid = 256 blocks exactly, 1 block/CU):
//   all blocks   : P1 code row b, P2 local top-4, P3 sub row b
//   b in [44,76) : P4 expert eighth (e = (b-44)>>3, q = (b-44)&7, 64 atoms)
//   b in [8,44)  : P5 recon (64 output dims each)
//   others       : retire after P3

__global__ void __launch_bounds__(256, 1) moe_fused(
    const float* __restrict__ x,
    const float* __restrict__ enc_top,
    const float* __restrict__ W_down,
    const float* __restrict__ enc_w,
    float* __restrict__ out,
    float* __restrict__ ws_f)
{
    u64* pc = (u64*)ws_f;           // [256][256]
    u64* ps = pc + 256 * 256;       // [8][256]
    u64* pd = ps + 8 * 256;         // [36][4][8][64]

    __shared__ float s_red[256];
    __shared__ float s_sub[SUB_DIM];
    __shared__ float s_ec[SUB_DIM];           // per-eighth atoms
    __shared__ float s_decp[16][SUB_DIM];     // decode partials / recon reduce buffer
    __shared__ float s_dec[SUB_DIM];
    __shared__ int   s_idx[TOPK];
    __shared__ float s_val[TOPK];

    const int b    = blockIdx.x;    // 0..255
    const int t    = threadIdx.x;   // 0..255
    const int lane = t & 63;
    const int wave = t >> 6;
    const float4* x4 = (const float4*)x;

    // ================= P1: code row b (256-thread dot, <=3 indep loads) =================
    {
        const float4* row4 = (const float4*)(enc_top + (size_t)b * INPUT_DIM);
        float acc = dot4(row4[t], x4[t]) + dot4(row4[t + 256], x4[t + 256]);
        if (t < 64) acc += dot4(row4[t + 512], x4[t + 512]);
        #pragma unroll
        for (int o = 32; o > 0; o >>= 1) acc += __shfl_down(acc, o);
        if (lane == 0) s_red[wave] = acc;
        __syncthreads();
        // every thread folds the 4 wave partials itself (no broadcast round trip)
        float c = (s_red[0] + s_red[1]) + (s_red[2] + s_red[3]);
        c = (c >= OFFSET) ? c : 0.0f;
        pair_st(&pc[(size_t)t * 256 + b], pack(c));   // one 8B store per thread -> reader t
    }

    // ================= P2: wave0 polls 256 codes, local top-4 =================
    if (wave == 0) {
        u64 v0, v1, v2, v3;
        for (;;) {
            v0 = pair_ld(&pc[(size_t)b * 256 + lane]);
            v1 = pair_ld(&pc[(size_t)b * 256 + lane + 64]);
            v2 = pair_ld(&pc[(size_t)b * 256 + lane + 128]);
            v3 = pair_ld(&pc[(size_t)b * 256 + lane + 192]);
            if (__all(pvalid(v0) && pvalid(v1) && pvalid(v2) && pvalid(v3))) break;
        }
        float v[4] = { payload(v0), payload(v1), payload(v2), payload(v3) };
        int   id[4] = { lane, lane + 64, lane + 128, lane + 192 };
        for (int k = 0; k < TOPK; ++k) {
            float bv = v[0]; int bi = id[0];
            #pragma unroll
            for (int i = 1; i < 4; ++i)
                if (v[i] > bv || (v[i] == bv && id[i] < bi)) { bv = v[i]; bi = id[i]; }
            #pragma unroll
            for (int o = 32; o > 0; o >>= 1) {
                float ov = __shfl_down(bv, o);
                int   oi = __shfl_down(bi, o);
                if (ov > bv || (ov == bv && oi < bi)) { bv = ov; bi = oi; }
            }
            bv = __shfl(bv, 0);
            bi = __shfl(bi, 0);
            if (lane == 0) { s_idx[k] = bi; s_val[k] = bv; }
            #pragma unroll
            for (int i = 0; i < 4; ++i)
                if (id[i] == bi) v[i] = -FLT_MAX;
        }
        // reset consumed pairs (off critical path)
        pair_st(&pc[(size_t)b * 256 + lane], 0ull);
        pair_st(&pc[(size_t)b * 256 + lane + 64], 0ull);
        pair_st(&pc[(size_t)b * 256 + lane + 128], 0ull);
        pair_st(&pc[(size_t)b * 256 + lane + 192], 0ull);
    }
    __syncthreads();

    // ===== P4 prefetch issue (expert blocks 44..75), fire-and-forget before P3 =====
    const float* Wq = nullptr;
    float pf = 0.0f;
    if (b >= 44 && b < 76) {
        const int eb = b - 44;
        const int e  = eb >> 3, q = eb & 7;
        Wq = enc_w + ((size_t)s_idx[e] * ATOMS + (size_t)q * 64) * SUB_DIM;
        // touch one float4 per 64B line: 256 lines / 256 threads = 1 each
        float4 w = ((const float4*)Wq)[(size_t)t * 4];
        pf = w.x + w.w;
    }

    // ================= P3: sub row b (256-thread dot) =================
    {
        const int E = s_idx[b >> 6];
        const float4* row4 = (const float4*)(W_down + ((size_t)E * SUB_DIM + (b & 63)) * INPUT_DIM);
        float acc = dot4(row4[t], x4[t]) + dot4(row4[t + 256], x4[t + 256]);
        if (t < 64) acc += dot4(row4[t + 512], x4[t + 512]);
        #pragma unroll
        for (int o = 32; o > 0; o >>= 1) acc += __shfl_down(acc, o);
        if (lane == 0) s_red[wave] = acc;
        __syncthreads();
        float s = (s_red[0] + s_red[1]) + (s_red[2] + s_red[3]);
        if (t < 8) pair_st(&ps[(size_t)t * 256 + b], pack(s));   // 8 eighth copies, parallel lanes
    }

    if (b < 8 || b >= 76) return;     // plain producers retire

    // ================= P4: expert encode+decode, 8 eighth-blocks per expert =================
    if (b >= 44) {
        const int eb = b - 44;
        const int e  = eb >> 3, q = eb & 7;
        if (wave == 0) {
            u64 v;
            for (;;) {
                v = pair_ld(&ps[(size_t)q * 256 + e * SUB_DIM + lane]);
                if (__all(pvalid(v))) break;
            }
            s_sub[lane] = payload(v);
            pair_st(&ps[(size_t)q * 256 + e * SUB_DIM + lane], 0ull);
        }
        asm volatile("" :: "v"(pf));   // keep prefetch alive
        __syncthreads();
        // encode: 1 atom per thread (64 atoms in this eighth)
        if (t < 64) {
            const float4* row4 = (const float4*)(Wq + (size_t)t * SUB_DIM);
            float acc = 0.0f;
            #pragma unroll
            for (int i = 0; i < SUB_DIM / 4; ++i) {
                float4 w = row4[i];
                acc += w.x * s_sub[4*i] + w.y * s_sub[4*i+1] + w.z * s_sub[4*i+2] + w.w * s_sub[4*i+3];
            }
            s_ec[t] = (acc >= OFFSET) ? acc : 0.01f * acc;   // leaky slope .01
        }
        __syncthreads();
        // decode partial over 64 atoms: thread (ch=t>>4, sg=t&15) -> 4 atoms x 4 s-cols
        {
            const int sg = t & 15, ch = t >> 4;
            float4 a4 = make_float4(0.f, 0.f, 0.f, 0.f);
            #pragma unroll
            for (int aa = ch * 4; aa < ch * 4 + 4; ++aa) {
                float4 w = *(const float4*)(Wq + (size_t)aa * SUB_DIM + sg * 4);
                float  ec = s_ec[aa];
                a4.x += w.x * ec; a4.y += w.y * ec; a4.z += w.z * ec; a4.w += w.w * ec;
            }
            *(float4*)&s_decp[ch][sg * 4] = a4;
        }
        __syncthreads();
        if (t < SUB_DIM) {
            float d = 0.0f;
            #pragma unroll
            for (int c = 0; c < 16; ++c) d += s_decp[c][t];
            s_dec[t] = d;
        }
        __syncthreads();
        // fan-out eighth-partial dec to 36 readers
        {
            const u64 pv = pack(s_dec[lane]);
            #pragma unroll
            for (int i = 0; i < 9; ++i) {
                const int r = wave + 4 * i;   // 0..35
                pair_st(&pd[(((size_t)r * TOPK + e) * 8 + q) * 64 + lane], pv);
            }
        }
        return;
    }

    // ================= P5: recon (blocks 8..43); W preloaded during P4 window =================
    {
        const int rb = b - 8;                  // 0..35
        const int d  = rb * 64 + lane;
        const int E  = s_idx[wave];            // one expert per wave
        float wr[SUB_DIM];
        const float* Wb = W_down + (size_t)E * SUB_DIM * INPUT_DIM + d;
        #pragma unroll
        for (int s = 0; s < SUB_DIM; ++s) wr[s] = Wb[(size_t)s * INPUT_DIM];
        const float et = s_val[wave] * enc_top[(size_t)E * INPUT_DIM + d];
        // poll the 8 eighth-dec partials for this wave's expert
        const size_t base = ((size_t)rb * TOPK + wave) * 8 * 64 + lane;
        u64 v0, v1, v2, v3, v4, v5, v6, v7;
        for (;;) {
            v0 = pair_ld(&pd[base]);
            v1 = pair_ld(&pd[base + 64]);
            v2 = pair_ld(&pd[base + 128]);
            v3 = pair_ld(&pd[base + 192]);
            v4 = pair_ld(&pd[base + 256]);
            v5 = pair_ld(&pd[base + 320]);
            v6 = pair_ld(&pd[base + 384]);
            v7 = pair_ld(&pd[base + 448]);
            if (__all(pvalid(v0) && pvalid(v1) && pvalid(v2) && pvalid(v3) &&
                      pvalid(v4) && pvalid(v5) && pvalid(v6) && pvalid(v7))) break;
        }
        float dv = ((payload(v0) + payload(v1)) + (payload(v2) + payload(v3)))
                 + ((payload(v4) + payload(v5)) + (payload(v6) + payload(v7)));
        pair_st(&pd[base], 0ull);
        pair_st(&pd[base + 64], 0ull);
        pair_st(&pd[base + 128], 0ull);
        pair_st(&pd[base + 192], 0ull);
        pair_st(&pd[base + 256], 0ull);
        pair_st(&pd[base + 320], 0ull);
        pair_st(&pd[base + 384], 0ull);
        pair_st(&pd[base + 448], 0ull);
        // split-accumulator shfl dot (depth ~16 instead of 64)
        float a0 = 0.f, a1 = 0.f, a2 = 0.f, a3 = 0.f;
        #pragma unroll
        for (int s = 0; s < SUB_DIM; s += 4) {
            a0 += wr[s]     * __shfl(dv, s);
            a1 += wr[s + 1] * __shfl(dv, s + 1);
            a2 += wr[s + 2] * __shfl(dv, s + 2);
            a3 += wr[s + 3] * __shfl(dv, s + 3);
        }
        // cross-wave reduce in s_decp (distinct from P3's s_red -> no barrier needed before)
        float* red = (float*)s_decp;
        red[t] = et + ((a0 + a1) + (a2 + a3));
        __syncthreads();
        if (t < 64)
            out[rb * 64 + t] = red[t] + red[t + 64] + red[t + 128] + red[t + 192];
    }
}

extern "C" void kernel_launch(void* const* d_in, const int* in_sizes, int n_in,
                              void* d_out, int out_size, void* d_ws, size_t ws_size,
                              hipStream_t stream) {
    const float* x       = (const float*)d_in[0];
    const float* enc_top = (const float*)d_in[1];
    const float* W_down  = (const float*)d_in[2];
    const float* enc_w   = (const float*)d_in[3];
    float* out = (float*)d_out;
    float* ws  = (float*)d_ws;

    moe_fused<<<dim3(256), dim3(256), 0, stream>>>(x, enc_top, W_down, enc_w, out, ws);
}